// Round 19
// baseline (96.393 us; speedup 1.0000x reference)
//
#include <hip/hip_runtime.h>
#include <math.h>

#define EPS 1e-8f

constexpr int B_ = 128;     // batch
constexpr int Q_ = 20;      // queries per sample
constexpr int D_ = 11;      // feature dim
constexpr int N_ = 100000;  // songs
constexpr int DP_ = 12;     // padded feature dim (3x float4)
constexpr int NPAIR = B_ * Q_;  // 2560
constexpr int NCH = 1000;   // song chunks
constexpr int CS = N_ / NCH;    // 100 songs per chunk
constexpr int NG = CS / 4;      // 25 4-song groups per chunk
constexpr int TPB = 128;
constexpr int PPT = 4;      // pairs per thread (A,B,C,D)
constexpr int REP = NPAIR / (PPT * TPB);   // 5 pair-blocks
constexpr int CPB = 2;      // chunks per block (write-late double buffer)
constexpr int NPB = NCH / CPB;             // 500 chunk-pairs
constexpr int MPAD = (NPB + 7) / 8;        // 63
constexpr int SGRID = 8 * MPAD * REP;      // 2520 (guards for 500 % 8 != 0)
constexpr int LHALF = NG * 6;              // 150 float4s staged per chunk (songs 0,1 of each group)

typedef __attribute__((ext_vector_type(4))) float f4;

// ---------------- fused prep: MLP encoder + song pre-normalization ---------------
__global__ void prep_kernel(const float* __restrict__ x,
                            const float* __restrict__ W1, const float* __restrict__ b1,
                            const float* __restrict__ W2, const float* __restrict__ b2,
                            const float* __restrict__ W3, const float* __restrict__ b3,
                            const float* __restrict__ songs,
                            float* __restrict__ pnorm, float* __restrict__ snorm,
                            int do_snorm)
{
    const int t = threadIdx.x;
    if (blockIdx.x >= B_) {
        if (!do_snorm) return;
        const int i = (blockIdx.x - B_) * blockDim.x + t;
        if (i >= N_) return;
        float v[DP_]; float ss = 0.0f;
#pragma unroll
        for (int d = 0; d < D_; ++d) { v[d] = songs[(size_t)i * D_ + d]; ss += v[d] * v[d]; }
        float nrm = fmaxf(sqrtf(ss), EPS);
#pragma unroll
        for (int d = 0; d < D_; ++d) v[d] /= nrm;
        v[D_] = 0.0f;
        float4* o = reinterpret_cast<float4*>(snorm + (size_t)i * DP_);
        o[0] = make_float4(v[0], v[1], v[2], v[3]);
        o[1] = make_float4(v[4], v[5], v[6], v[7]);
        o[2] = make_float4(v[8], v[9], v[10], v[11]);
        return;
    }
    __shared__ float xr[55];
    __shared__ float h1[128];
    __shared__ float h2[64];
    __shared__ float prod[220];
    const int b = blockIdx.x;
    if (t < 55) xr[t] = x[b * 55 + t];
    __syncthreads();
    if (t < 128) {
        float s = b1[t];
        for (int k = 0; k < 55; ++k) s += xr[k] * W1[k * 128 + t];
        h1[t] = fmaxf(s, 0.0f);
    }
    __syncthreads();
    if (t < 64) {
        float s = b2[t];
        for (int k = 0; k < 128; ++k) s += h1[k] * W2[k * 64 + t];
        h2[t] = fmaxf(s, 0.0f);
    }
    __syncthreads();
    if (t < 220) {
        float s = b3[t];
        for (int k = 0; k < 64; ++k) s += h2[k] * W3[k * 220 + t];
        prod[t] = s;
    }
    __syncthreads();
    if (t < Q_) {
        float ss = 0.0f;
        for (int d = 0; d < D_; ++d) { float v = prod[t * D_ + d]; ss += v * v; }
        float nrm = fmaxf(sqrtf(ss), EPS);
        float* o = pnorm + (b * Q_ + t) * DP_;
        for (int d = 0; d < D_; ++d) o[d] = prod[t * D_ + d] / nrm;
        o[D_] = 0.0f;
    }
}

// dot over 11 dims, fixed fmaf sequence (deterministic, identical at every call site)
__device__ __forceinline__ float dot11v(f4 qa, f4 qb, f4 qc,
                                        float4 a, float4 b, float4 c)
{
    float x = qa.x * a.x;
    x = fmaf(qa.y, a.y, x);
    x = fmaf(qa.z, a.z, x);
    x = fmaf(qa.w, a.w, x);
    x = fmaf(qb.x, b.x, x);
    x = fmaf(qb.y, b.y, x);
    x = fmaf(qb.z, b.z, x);
    x = fmaf(qb.w, b.w, x);
    x = fmaf(qc.x, c.x, x);
    x = fmaf(qc.y, c.y, x);
    x = fmaf(qc.z, c.z, x);
    return x;
}

// monotone float -> uint32 (strictly order-preserving for non-NaN)
__device__ __forceinline__ unsigned int fkey(float f)
{
    unsigned int b = __float_as_uint(f);
    return (b & 0x80000000u) ? ~b : (b | 0x80000000u);
}

// pack (value, index): high = monotone value, low = ~idx so that for equal values
// atomicMax keeps the SMALLER index (numpy first-index argmax semantics)
__device__ __forceinline__ unsigned long long pack_vi(float v, int idx)
{
    return ((unsigned long long)fkey(v) << 32) | (unsigned long long)(0xFFFFFFFFu - (unsigned int)idx);
}

// Inline-asm query load: asm outputs CANNOT be rematerialized -> the float4s stay
// resident. EARLY-CLOBBER (=&v) mandatory (round-12 crash: dest aliased the addr).
#define QLOAD(P, PTR) \
    asm volatile("global_load_dwordx4 %0, %3, off\n\t" \
                 "global_load_dwordx4 %1, %3, off offset:16\n\t" \
                 "global_load_dwordx4 %2, %3, off offset:32" \
                 : "=&v"(q##P##a), "=&v"(q##P##b), "=&v"(q##P##c) \
                 : "v"(PTR) : "memory")

// s_waitcnt with all 12 vectors as in/outs: every consumer is data-dependent.
#define QWAIT() \
    asm volatile("s_waitcnt vmcnt(0)" \
                 : "+v"(qAa), "+v"(qAb), "+v"(qAc), "+v"(qBa), "+v"(qBb), "+v"(qBc), \
                   "+v"(qCa), "+v"(qCb), "+v"(qCc), "+v"(qDa), "+v"(qDb), "+v"(qDc) \
                 :: "memory")

#define PMAXV(P, GCUR) { \
    float d0 = dot11v(q##P##a, q##P##b, q##P##c, s0, s1,  s2);  \
    float d1 = dot11v(q##P##a, q##P##b, q##P##c, s3, s4,  s5);  \
    float d2 = dot11v(q##P##a, q##P##b, q##P##c, s6, s7,  s8);  \
    float d3 = dot11v(q##P##a, q##P##b, q##P##c, s9, s10, s11); \
    float mx = fmaxf(fmaxf(d0, d1), fmaxf(d2, d3)); \
    if (mx > bv##P) { bv##P = mx; gi##P = (GCUR); } \
}

// Split-source group step: songs 0,1 from compact LDS (6 float4s at GIDX*6),
// songs 2,3 from snorm in L2 via wave-uniform global loads (GP = chunk f4 base).
// Halves the LDS-pipe instruction count -- the round-18 measured bottleneck
// (3M ds_read_b128 x ~12cyc = 59us of LDS pipe vs 44us VALU).
#define GSTEP(L4, GP, GIDX, GOFF) { \
    const float4* vg = (L4) + (GIDX) * 6; \
    float4 s0 = vg[0], s1 = vg[1], s2 = vg[2], s3 = vg[3], s4 = vg[4], s5 = vg[5]; \
    const float4* wg = (GP) + (GIDX) * 12 + 6; \
    float4 s6 = wg[0], s7 = wg[1], s8 = wg[2], s9 = wg[3], s10 = wg[4], s11 = wg[5]; \
    PMAXV(A, (GOFF) + (GIDX)) PMAXV(B, (GOFF) + (GIDX)) \
    PMAXV(C, (GOFF) + (GIDX)) PMAXV(D, (GOFF) + (GIDX)) \
}

#define FINI(P, POFF) { \
    int gsel = gi##P; \
    int cs = (gsel >= NG) ? 1 : 0; \
    int gg = gsel - cs * NG; \
    const float4* vg = reinterpret_cast<const float4*>(lds[cs]) + gg * 6; \
    float4 s0 = vg[0], s1 = vg[1], s2 = vg[2], s3 = vg[3], s4 = vg[4], s5 = vg[5]; \
    const float4* wg = s40 + (size_t)cs * CS * 3 + gg * 12 + 6; \
    float4 s6 = wg[0], s7 = wg[1], s8 = wg[2], s9 = wg[3], s10 = wg[4], s11 = wg[5]; \
    float d0 = dot11v(q##P##a, q##P##b, q##P##c, s0, s1,  s2);  \
    float d1 = dot11v(q##P##a, q##P##b, q##P##c, s3, s4,  s5);  \
    float d2 = dot11v(q##P##a, q##P##b, q##P##c, s6, s7,  s8);  \
    float d3 = dot11v(q##P##a, q##P##b, q##P##c, s9, s10, s11); \
    int base = (c0 + cs) * CS + gg * 4; \
    int idx = base; \
    if (d3 == bv##P) idx = base + 3; \
    if (d2 == bv##P) idx = base + 2; \
    if (d1 == bv##P) idx = base + 1; \
    if (d0 == bv##P) idx = base; \
    atomicMax(&res[jb + (POFF) * TPB], pack_vi(bv##P, idx)); \
}

// ---------------- sim + global argmax: split LDS/L2 song sources ------------------
// XCD-swizzled 1-D grid (sim13 structure). LDS stages only songs {4g, 4g+1} of
// each group (compact 150 f4/chunk); songs {4g+2, 4g+3} are read straight from
// snorm (L2-resident per XCD). LDS reads AND staging writes halve.
__global__ __launch_bounds__(TPB, 2)
void sim19_kernel(const float* __restrict__ pnorm,
                  const float* __restrict__ snorm,
                  unsigned long long* __restrict__ res)
{
    __shared__ __align__(16) float lds[CPB][LHALF * 4];   // 2 x 2400 B
    const int bid = blockIdx.x;
    const int u = bid & 7;
    const int kk = bid >> 3;
    const int r = kk % REP;
    const int m = kk / REP;
    const int cpair = u + 8 * m;
    if (cpair >= NPB) return;                  // guard (500 % 8 != 0)
    const int t = threadIdx.x;
    const int c0 = cpair * CPB;

    const float4* s40 = reinterpret_cast<const float4*>(snorm) + (size_t)c0 * CS * 3;
    const float4* s41 = s40 + CS * 3;
    float4* b0 = reinterpret_cast<float4*>(lds[0]);
    float4* b1 = reinterpret_cast<float4*>(lds[1]);

    // stage chunk c0 compact half (150 f4): slot f=(g*6+i) <- src g*12+i
    {
        int g = t / 6, i = t - g * 6;
        b0[t] = s40[g * 12 + i];
        int f2 = t + TPB;
        if (f2 < LHALF) {
            int g2 = f2 / 6, i2 = f2 - g2 * 6;
            b0[f2] = s40[g2 * 12 + i2];
        }
    }

    // query loads via inline asm (un-rematerializable -> resident)
    const int jb = r * (PPT * TPB) + t;
    f4 qAa, qAb, qAc, qBa, qBb, qBc, qCa, qCb, qCc, qDa, qDb, qDc;
    {
        const float* qp0 = pnorm + (size_t)(jb + 0 * TPB) * DP_;
        const float* qp1 = pnorm + (size_t)(jb + 1 * TPB) * DP_;
        const float* qp2 = pnorm + (size_t)(jb + 2 * TPB) * DP_;
        const float* qp3 = pnorm + (size_t)(jb + 3 * TPB) * DP_;
        QLOAD(A, qp0);
        QLOAD(B, qp1);
        QLOAD(C, qp2);
        QLOAD(D, qp3);
    }
    QWAIT();

    // issue chunk c1 compact-half loads now; LDS write deferred to after c0 compute
    float4 r0, r1 = make_float4(0.f, 0.f, 0.f, 0.f);
    {
        int g = t / 6, i = t - g * 6;
        r0 = s41[g * 12 + i];
        int f2 = t + TPB;
        if (f2 < LHALF) {
            int g2 = f2 / 6, i2 = f2 - g2 * 6;
            r1 = s41[g2 * 12 + i2];
        }
    }

    __syncthreads();

    float bvA = -1e30f, bvB = -1e30f, bvC = -1e30f, bvD = -1e30f;
    int giA = 0, giB = 0, giC = 0, giD = 0;

#pragma unroll 2
    for (int g = 0; g < NG; ++g) {
        GSTEP(b0, s40, g, 0);
    }

    // write-late: c1 data arrived long ago; store + barrier, then compute
    b1[t] = r0;
    if (t + TPB < LHALF) b1[t + TPB] = r1;
    __syncthreads();

#pragma unroll 2
    for (int g = 0; g < NG; ++g) {
        GSTEP(b1, s41, g, NG);
    }

    // Recompute winning group from the identical sources -> bit-exact;
    // descending cascade picks the FIRST in-group index achieving the max.
    FINI(A, 0) FINI(B, 1) FINI(C, 2) FINI(D, 3)
}

// ---------------- fallback (no snorm workspace): global loads, on-the-fly norm ----
template<int FNCH>
__global__ void sim6f_kernel(const float* __restrict__ pnorm,
                             const float* __restrict__ songs,
                             unsigned long long* __restrict__ res)
{
    constexpr int FCS = N_ / FNCH;
    const int chunk = blockIdx.x;
    const int j = blockIdx.y * 256 + threadIdx.x;

    float qv[D_];
#pragma unroll
    for (int d = 0; d < D_; ++d) qv[d] = pnorm[j * DP_ + d];

    float bestv = -1e30f;
    int   besti = 0;
    const int base = chunk * FCS;
    for (int i = base; i < base + FCS; ++i) {
        float sv[D_]; float ss = 0.0f;
#pragma unroll
        for (int d = 0; d < D_; ++d) { sv[d] = songs[(size_t)i * D_ + d]; ss += sv[d] * sv[d]; }
        float nrm = fmaxf(sqrtf(ss), EPS);
        float a = qv[0] * (sv[0] / nrm);
#pragma unroll
        for (int d = 1; d < D_; ++d) a = fmaf(qv[d], sv[d] / nrm, a);
        if (a > bestv) { bestv = a; besti = i; }
    }
    atomicMax(&res[j], pack_vi(bestv, besti));
}

// ---------------- decode + gather ------------------------------------------------
__global__ void gather_kernel(const unsigned long long* __restrict__ res,
                              const float* __restrict__ songs, float* __restrict__ out)
{
    const int j = blockIdx.x * blockDim.x + threadIdx.x;
    if (j >= NPAIR) return;
    const unsigned int idx = 0xFFFFFFFFu - (unsigned int)(res[j] & 0xFFFFFFFFull);
#pragma unroll
    for (int d = 0; d < D_; ++d) out[(size_t)j * D_ + d] = songs[(size_t)idx * D_ + d];
}

extern "C" void kernel_launch(void* const* d_in, const int* in_sizes, int n_in,
                              void* d_out, int out_size, void* d_ws, size_t ws_size,
                              hipStream_t stream)
{
    const float* x     = (const float*)d_in[0];
    const float* W1    = (const float*)d_in[1];
    const float* b1    = (const float*)d_in[2];
    const float* W2    = (const float*)d_in[3];
    const float* b2    = (const float*)d_in[4];
    const float* W3    = (const float*)d_in[5];
    const float* b3    = (const float*)d_in[6];
    const float* songs = (const float*)d_in[7];
    float* out = (float*)d_out;

    constexpr size_t PN = (size_t)NPAIR * DP_;      // pnorm floats
    constexpr size_t SN = (size_t)N_ * DP_;         // snorm floats
    float* pnorm = (float*)d_ws;
    constexpr int SNB = (N_ + 255) / 256;

    const size_t need_full = (PN + SN) * sizeof(float) + (size_t)NPAIR * 8 + 64;
    const size_t need_min  = PN * sizeof(float) + (size_t)NPAIR * 8 + 64;

    if (ws_size >= need_full) {
        float* snorm = pnorm + PN;
        unsigned long long* res =
            (unsigned long long*)(((uintptr_t)(snorm + SN) + 7) & ~(uintptr_t)7);
        hipMemsetAsync(res, 0, (size_t)NPAIR * 8, stream);
        prep_kernel<<<B_ + SNB, 256, 0, stream>>>(x, W1, b1, W2, b2, W3, b3, songs,
                                                  pnorm, snorm, 1);
        sim19_kernel<<<SGRID, TPB, 0, stream>>>(pnorm, snorm, res);
        gather_kernel<<<(NPAIR + 255) / 256, 256, 0, stream>>>(res, songs, out);
    } else if (ws_size >= need_min) {
        unsigned long long* res =
            (unsigned long long*)(((uintptr_t)(pnorm + PN) + 7) & ~(uintptr_t)7);
        hipMemsetAsync(res, 0, (size_t)NPAIR * 8, stream);
        prep_kernel<<<B_, 256, 0, stream>>>(x, W1, b1, W2, b2, W3, b3, songs,
                                            pnorm, nullptr, 0);
        constexpr int FNCH = 250;
        sim6f_kernel<FNCH><<<dim3(FNCH, NPAIR / 256), 256, 0, stream>>>(pnorm, songs, res);
        gather_kernel<<<(NPAIR + 255) / 256, 256, 0, stream>>>(res, songs, out);
    }
}

// Round 20
// 86.736 us; speedup vs baseline: 1.1113x; 1.1113x over previous
//
#include <hip/hip_runtime.h>
#include <math.h>

#define EPS 1e-8f

constexpr int B_ = 128;     // batch
constexpr int Q_ = 20;      // queries per sample
constexpr int D_ = 11;      // feature dim
constexpr int N_ = 100000;  // songs
constexpr int DP_ = 12;     // padded feature dim (3x float4)
constexpr int NPAIR = B_ * Q_;  // 2560
constexpr int NCH = 1000;   // song chunks
constexpr int CS = N_ / NCH;    // 100 songs per chunk
constexpr int NG = CS / 4;      // 25 4-song groups per chunk
constexpr int TPB = 128;
constexpr int PPT = 4;      // pairs per thread (A,B,C,D)
constexpr int REP = NPAIR / (PPT * TPB);   // 5 pair-blocks
constexpr int CPB = 2;      // chunks per block (write-late double buffer)
constexpr int NPB = NCH / CPB;             // 500 chunk-pairs
constexpr int MPAD = (NPB + 7) / 8;        // 63
constexpr int SGRID = 8 * MPAD * REP;      // 2520 (guards for 500 % 8 != 0)

typedef __attribute__((ext_vector_type(4))) float f4;

// ---------------- fused prep: MLP encoder + song pre-normalization + res zero -----
__global__ void prep_kernel(const float* __restrict__ x,
                            const float* __restrict__ W1, const float* __restrict__ b1,
                            const float* __restrict__ W2, const float* __restrict__ b2,
                            const float* __restrict__ W3, const float* __restrict__ b3,
                            const float* __restrict__ songs,
                            float* __restrict__ pnorm, float* __restrict__ snorm,
                            unsigned long long* __restrict__ res,
                            int do_snorm)
{
    const int t = threadIdx.x;
    if (blockIdx.x >= B_) {
        if (!do_snorm) return;
        const int zb = blockIdx.x - B_;
        // zero the atomicMax result buffer (replaces a separate memset dispatch)
        const int zi = zb * 256 + t;
        if (zi < NPAIR) res[zi] = 0ull;
        const int i = zb * blockDim.x + t;
        if (i >= N_) return;
        float v[DP_]; float ss = 0.0f;
#pragma unroll
        for (int d = 0; d < D_; ++d) { v[d] = songs[(size_t)i * D_ + d]; ss += v[d] * v[d]; }
        float nrm = fmaxf(sqrtf(ss), EPS);
#pragma unroll
        for (int d = 0; d < D_; ++d) v[d] /= nrm;
        v[D_] = 0.0f;
        float4* o = reinterpret_cast<float4*>(snorm + (size_t)i * DP_);
        o[0] = make_float4(v[0], v[1], v[2], v[3]);
        o[1] = make_float4(v[4], v[5], v[6], v[7]);
        o[2] = make_float4(v[8], v[9], v[10], v[11]);
        return;
    }
    __shared__ float xr[55];
    __shared__ float h1[128];
    __shared__ float h2[64];
    __shared__ float prod[220];
    const int b = blockIdx.x;
    if (t < 55) xr[t] = x[b * 55 + t];
    __syncthreads();
    if (t < 128) {
        float s = b1[t];
        for (int k = 0; k < 55; ++k) s += xr[k] * W1[k * 128 + t];
        h1[t] = fmaxf(s, 0.0f);
    }
    __syncthreads();
    if (t < 64) {
        float s = b2[t];
        for (int k = 0; k < 128; ++k) s += h1[k] * W2[k * 64 + t];
        h2[t] = fmaxf(s, 0.0f);
    }
    __syncthreads();
    if (t < 220) {
        float s = b3[t];
        for (int k = 0; k < 64; ++k) s += h2[k] * W3[k * 220 + t];
        prod[t] = s;
    }
    __syncthreads();
    if (t < Q_) {
        float ss = 0.0f;
        for (int d = 0; d < D_; ++d) { float v = prod[t * D_ + d]; ss += v * v; }
        float nrm = fmaxf(sqrtf(ss), EPS);
        float* o = pnorm + (b * Q_ + t) * DP_;
        for (int d = 0; d < D_; ++d) o[d] = prod[t * D_ + d] / nrm;
        o[D_] = 0.0f;
    }
}

// dot over 11 dims, fixed fmaf sequence (deterministic, identical at every call site)
__device__ __forceinline__ float dot11v(f4 qa, f4 qb, f4 qc,
                                        float4 a, float4 b, float4 c)
{
    float x = qa.x * a.x;
    x = fmaf(qa.y, a.y, x);
    x = fmaf(qa.z, a.z, x);
    x = fmaf(qa.w, a.w, x);
    x = fmaf(qb.x, b.x, x);
    x = fmaf(qb.y, b.y, x);
    x = fmaf(qb.z, b.z, x);
    x = fmaf(qb.w, b.w, x);
    x = fmaf(qc.x, c.x, x);
    x = fmaf(qc.y, c.y, x);
    x = fmaf(qc.z, c.z, x);
    return x;
}

// monotone float -> uint32 (strictly order-preserving for non-NaN)
__device__ __forceinline__ unsigned int fkey(float f)
{
    unsigned int b = __float_as_uint(f);
    return (b & 0x80000000u) ? ~b : (b | 0x80000000u);
}

// pack (value, index): high = monotone value, low = ~idx so that for equal values
// atomicMax keeps the SMALLER index (numpy first-index argmax semantics)
__device__ __forceinline__ unsigned long long pack_vi(float v, int idx)
{
    return ((unsigned long long)fkey(v) << 32) | (unsigned long long)(0xFFFFFFFFu - (unsigned int)idx);
}

// Inline-asm query load: asm outputs CANNOT be rematerialized -> the float4s stay
// resident. EARLY-CLOBBER (=&v) mandatory (round-12 crash: dest aliased the addr).
#define QLOAD(P, PTR) \
    asm volatile("global_load_dwordx4 %0, %3, off\n\t" \
                 "global_load_dwordx4 %1, %3, off offset:16\n\t" \
                 "global_load_dwordx4 %2, %3, off offset:32" \
                 : "=&v"(q##P##a), "=&v"(q##P##b), "=&v"(q##P##c) \
                 : "v"(PTR) : "memory")

// s_waitcnt with all 12 vectors as in/outs: every consumer is data-dependent.
#define QWAIT() \
    asm volatile("s_waitcnt vmcnt(0)" \
                 : "+v"(qAa), "+v"(qAb), "+v"(qAc), "+v"(qBa), "+v"(qBb), "+v"(qBc), \
                   "+v"(qCa), "+v"(qCb), "+v"(qCc), "+v"(qDa), "+v"(qDb), "+v"(qDc) \
                 :: "memory")

#define PMAXV(P, GCUR) { \
    float d0 = dot11v(q##P##a, q##P##b, q##P##c, s0, s1,  s2);  \
    float d1 = dot11v(q##P##a, q##P##b, q##P##c, s3, s4,  s5);  \
    float d2 = dot11v(q##P##a, q##P##b, q##P##c, s6, s7,  s8);  \
    float d3 = dot11v(q##P##a, q##P##b, q##P##c, s9, s10, s11); \
    float mx = fmaxf(fmaxf(d0, d1), fmaxf(d2, d3)); \
    if (mx > bv##P) { bv##P = mx; gi##P = (GCUR); } \
}

// Group-index parameter named GIDX so pair letters are never captured (r14 lesson).
#define GSTEP(L4, GIDX, GOFF) { \
    const float4* vg = (L4) + (GIDX) * 12; \
    float4 s0 = vg[0], s1 = vg[1], s2  = vg[2],  s3  = vg[3],  s4  = vg[4],  s5  = vg[5]; \
    float4 s6 = vg[6], s7 = vg[7], s8  = vg[8],  s9  = vg[9],  s10 = vg[10], s11 = vg[11]; \
    PMAXV(A, (GOFF) + (GIDX)) PMAXV(B, (GOFF) + (GIDX)) \
    PMAXV(C, (GOFF) + (GIDX)) PMAXV(D, (GOFF) + (GIDX)) \
}

#define FINI(P, POFF) { \
    int gsel = gi##P; \
    int cs = (gsel >= NG) ? 1 : 0; \
    int gg = gsel - cs * NG; \
    const float4* vg = reinterpret_cast<const float4*>(lds[cs]) + gg * 12; \
    float4 s0 = vg[0], s1 = vg[1], s2  = vg[2],  s3  = vg[3],  s4  = vg[4],  s5  = vg[5]; \
    float4 s6 = vg[6], s7 = vg[7], s8  = vg[8],  s9  = vg[9],  s10 = vg[10], s11 = vg[11]; \
    float d0 = dot11v(q##P##a, q##P##b, q##P##c, s0, s1,  s2);  \
    float d1 = dot11v(q##P##a, q##P##b, q##P##c, s3, s4,  s5);  \
    float d2 = dot11v(q##P##a, q##P##b, q##P##c, s6, s7,  s8);  \
    float d3 = dot11v(q##P##a, q##P##b, q##P##c, s9, s10, s11); \
    int base = (c0 + cs) * CS + gg * 4; \
    int idx = base; \
    if (d3 == bv##P) idx = base + 3; \
    if (d2 == bv##P) idx = base + 2; \
    if (d1 == bv##P) idx = base + 1; \
    if (d0 == bv##P) idx = base; \
    atomicMax(&res[jb + (POFF) * TPB], pack_vi(bv##P, idx)); \
}

// ---------------- sim + global argmax: asm-pinned queries, LDS chunks -------------
// Best-known configuration (round 13, 83.7us): XCD-swizzled 1-D grid, two chunks
// per block (c1 write-late), 12 uniform ds_read_b128 per 176 pinned-operand FMAs.
__global__ __launch_bounds__(TPB, 2)
void sim13_kernel(const float* __restrict__ pnorm,
                  const float* __restrict__ snorm,
                  unsigned long long* __restrict__ res)
{
    __shared__ __align__(16) float lds[CPB][CS * DP_];   // 2 x 4800 B
    const int bid = blockIdx.x;
    const int u = bid & 7;
    const int kk = bid >> 3;
    const int r = kk % REP;
    const int m = kk / REP;
    const int cpair = u + 8 * m;
    if (cpair >= NPB) return;                  // guard (500 % 8 != 0)
    const int t = threadIdx.x;
    const int c0 = cpair * CPB;

    const float4* s40 = reinterpret_cast<const float4*>(snorm) + (size_t)c0 * CS * 3;
    const float4* s41 = s40 + CS * 3;
    float4* b0 = reinterpret_cast<float4*>(lds[0]);
    float4* b1 = reinterpret_cast<float4*>(lds[1]);

    // stage chunk c0 (300 float4s)
    b0[t] = s40[t];
    b0[t + TPB] = s40[t + TPB];
    if (t < CS * 3 - 2 * TPB) b0[t + 2 * TPB] = s40[t + 2 * TPB];

    // query loads via inline asm (un-rematerializable -> resident)
    const int jb = r * (PPT * TPB) + t;
    f4 qAa, qAb, qAc, qBa, qBb, qBc, qCa, qCb, qCc, qDa, qDb, qDc;
    {
        const float* qp0 = pnorm + (size_t)(jb + 0 * TPB) * DP_;
        const float* qp1 = pnorm + (size_t)(jb + 1 * TPB) * DP_;
        const float* qp2 = pnorm + (size_t)(jb + 2 * TPB) * DP_;
        const float* qp3 = pnorm + (size_t)(jb + 3 * TPB) * DP_;
        QLOAD(A, qp0);
        QLOAD(B, qp1);
        QLOAD(C, qp2);
        QLOAD(D, qp3);
    }
    QWAIT();

    // issue chunk c1 loads now; LDS write deferred until after c0 compute
    float4 r0 = s41[t];
    float4 r1 = s41[t + TPB];
    float4 r2 = make_float4(0.f, 0.f, 0.f, 0.f);
    if (t < CS * 3 - 2 * TPB) r2 = s41[t + 2 * TPB];

    __syncthreads();

    float bvA = -1e30f, bvB = -1e30f, bvC = -1e30f, bvD = -1e30f;
    int giA = 0, giB = 0, giC = 0, giD = 0;

    for (int g = 0; g < NG; ++g) {
        GSTEP(b0, g, 0);
    }

    // write-late: c1 data arrived long ago; store + barrier, then compute
    b1[t] = r0;
    b1[t + TPB] = r1;
    if (t < CS * 3 - 2 * TPB) b1[t + 2 * TPB] = r2;
    __syncthreads();

    for (int g = 0; g < NG; ++g) {
        GSTEP(b1, g, NG);
    }

    // Recompute winning group with the identical fmaf sequence -> bit-exact;
    // descending cascade picks the FIRST in-group index achieving the max.
    FINI(A, 0) FINI(B, 1) FINI(C, 2) FINI(D, 3)
}

// ---------------- fallback (no snorm workspace): global loads, on-the-fly norm ----
template<int FNCH>
__global__ void sim6f_kernel(const float* __restrict__ pnorm,
                             const float* __restrict__ songs,
                             unsigned long long* __restrict__ res)
{
    constexpr int FCS = N_ / FNCH;
    const int chunk = blockIdx.x;
    const int j = blockIdx.y * 256 + threadIdx.x;

    float qv[D_];
#pragma unroll
    for (int d = 0; d < D_; ++d) qv[d] = pnorm[j * DP_ + d];

    float bestv = -1e30f;
    int   besti = 0;
    const int base = chunk * FCS;
    for (int i = base; i < base + FCS; ++i) {
        float sv[D_]; float ss = 0.0f;
#pragma unroll
        for (int d = 0; d < D_; ++d) { sv[d] = songs[(size_t)i * D_ + d]; ss += sv[d] * sv[d]; }
        float nrm = fmaxf(sqrtf(ss), EPS);
        float a = qv[0] * (sv[0] / nrm);
#pragma unroll
        for (int d = 1; d < D_; ++d) a = fmaf(qv[d], sv[d] / nrm, a);
        if (a > bestv) { bestv = a; besti = i; }
    }
    atomicMax(&res[j], pack_vi(bestv, besti));
}

// ---------------- decode + gather ------------------------------------------------
__global__ void gather_kernel(const unsigned long long* __restrict__ res,
                              const float* __restrict__ songs, float* __restrict__ out)
{
    const int j = blockIdx.x * blockDim.x + threadIdx.x;
    if (j >= NPAIR) return;
    const unsigned int idx = 0xFFFFFFFFu - (unsigned int)(res[j] & 0xFFFFFFFFull);
#pragma unroll
    for (int d = 0; d < D_; ++d) out[(size_t)j * D_ + d] = songs[(size_t)idx * D_ + d];
}

extern "C" void kernel_launch(void* const* d_in, const int* in_sizes, int n_in,
                              void* d_out, int out_size, void* d_ws, size_t ws_size,
                              hipStream_t stream)
{
    const float* x     = (const float*)d_in[0];
    const float* W1    = (const float*)d_in[1];
    const float* b1    = (const float*)d_in[2];
    const float* W2    = (const float*)d_in[3];
    const float* b2    = (const float*)d_in[4];
    const float* W3    = (const float*)d_in[5];
    const float* b3    = (const float*)d_in[6];
    const float* songs = (const float*)d_in[7];
    float* out = (float*)d_out;

    constexpr size_t PN = (size_t)NPAIR * DP_;      // pnorm floats
    constexpr size_t SN = (size_t)N_ * DP_;         // snorm floats
    float* pnorm = (float*)d_ws;
    constexpr int SNB = (N_ + 255) / 256;

    const size_t need_full = (PN + SN) * sizeof(float) + (size_t)NPAIR * 8 + 64;
    const size_t need_min  = PN * sizeof(float) + (size_t)NPAIR * 8 + 64;

    if (ws_size >= need_full) {
        float* snorm = pnorm + PN;
        unsigned long long* res =
            (unsigned long long*)(((uintptr_t)(snorm + SN) + 7) & ~(uintptr_t)7);
        prep_kernel<<<B_ + SNB, 256, 0, stream>>>(x, W1, b1, W2, b2, W3, b3, songs,
                                                  pnorm, snorm, res, 1);
        sim13_kernel<<<SGRID, TPB, 0, stream>>>(pnorm, snorm, res);
        gather_kernel<<<(NPAIR + 255) / 256, 256, 0, stream>>>(res, songs, out);
    } else if (ws_size >= need_min) {
        unsigned long long* res =
            (unsigned long long*)(((uintptr_t)(pnorm + PN) + 7) & ~(uintptr_t)7);
        hipMemsetAsync(res, 0, (size_t)NPAIR * 8, stream);
        prep_kernel<<<B_, 256, 0, stream>>>(x, W1, b1, W2, b2, W3, b3, songs,
                                            pnorm, nullptr, res, 0);
        constexpr int FNCH = 250;
        sim6f_kernel<FNCH><<<dim3(FNCH, NPAIR / 256), 256, 0, stream>>>(pnorm, songs, res);
        gather_kernel<<<(NPAIR + 255) / 256, 256, 0, stream>>>(res, songs, out);
    }
}